// Round 4
// baseline (277.544 us; speedup 1.0000x reference)
//
#include <hip/hip_runtime.h>
#include <stdint.h>

#define B_   32
#define CIN  256
#define COUT 512
#define HW_  4096
#define NT   64

typedef short  short8  __attribute__((ext_vector_type(8)));
typedef float  float4_ __attribute__((ext_vector_type(4)));

__device__ __forceinline__ unsigned f2bf(float f) {
    unsigned u = __float_as_uint(f);
    u += 0x7FFFu + ((u >> 16) & 1u);   // RNE to bf16
    return u >> 16;
}

// Kernel 0 (grid 64):
//  blocks 0..31  : zero P/T, ggbx[b][a] = g@Wg.T + bg + bx
//  blocks 32..63 : WxR fragment-linear repack of Wx (bf16)
//    entry e = ((w*8+kk)*4+ai)*64 + lane  holds Wx[a=w*64+ai*16+(lane&15)]
//                                              [k=kk*32+(lane>>4)*8 .. +7]
__global__ __launch_bounds__(256) void prep_kernel(
    const float* __restrict__ g, const float* __restrict__ Wg,
    const float* __restrict__ bg, const float* __restrict__ Wx,
    const float* __restrict__ bx,
    uint4* __restrict__ WxR, float* __restrict__ ggbx,
    float* __restrict__ P, float* __restrict__ T)
{
    int t = threadIdx.x;
    if (blockIdx.x >= 32) {
        int e = (blockIdx.x - 32) * 256 + t;
        int lane = e & 63, ai = (e >> 6) & 3, kk = (e >> 8) & 7, w = e >> 11;
        int a  = w * 64 + ai * 16 + (lane & 15);
        int kb = kk * 32 + (lane >> 4) * 8;
        const float4* s = (const float4*)(Wx + (size_t)a * 256 + kb);
        float4 u0 = s[0], u1 = s[1];
        uint4 pk;
        pk.x = f2bf(u0.x) | (f2bf(u0.y) << 16);
        pk.y = f2bf(u0.z) | (f2bf(u0.w) << 16);
        pk.z = f2bf(u1.x) | (f2bf(u1.y) << 16);
        pk.w = f2bf(u1.z) | (f2bf(u1.w) << 16);
        WxR[e] = pk;
        return;
    }
    int b = blockIdx.x;
    int i = b * 256 + t;
    P[i] = 0.f; T[i] = 0.f;

    __shared__ float gl[COUT];
    gl[t]       = g[b * COUT + t];
    gl[t + 256] = g[b * COUT + 256 + t];
    __syncthreads();

    float acc0 = bg[t] + bx[t], acc1 = 0.f;    // a = t, dual chain for ILP
    const float4* wr = (const float4*)(Wg + (size_t)t * COUT);
    #pragma unroll 8
    for (int co = 0; co < COUT / 4; co += 2) {
        float4 wv0 = wr[co],     gv0 = *(const float4*)&gl[co * 4];
        float4 wv1 = wr[co + 1], gv1 = *(const float4*)&gl[co * 4 + 4];
        acc0 += wv0.x * gv0.x + wv0.y * gv0.y + wv0.z * gv0.z + wv0.w * gv0.w;
        acc1 += wv1.x * gv1.x + wv1.y * gv1.y + wv1.z * gv1.z + wv1.w * gv1.w;
    }
    ggbx[b * 256 + t] = acc0 + acc1;
}

// Kernel 1: per (b, n-tile of 64): async-DMA fp32 x tile into LDS [c][n],
// MFMA GEMM (bf16 conversion at fragment build) + relu + Wf reduce -> raw,
// then fp32 pooling partials P/T via atomics.
__global__ __launch_bounds__(256, 2) void attn_main(
    const float* __restrict__ x, const char* __restrict__ WxR,
    const float* __restrict__ ggbx, const float* __restrict__ Wf,
    const float* __restrict__ bfs,
    float* __restrict__ P, float* __restrict__ T, float* __restrict__ raw)
{
    __shared__ float xTf[CIN * NT];            // [c][n] fp32, 64 KB
    __shared__ float att_part[4][NT];
    __shared__ float raw_l[NT];

    int bid = blockIdx.x;
    int b = bid >> 6, nt = bid & 63;
    int t = threadIdx.x, w = t >> 6, lane = t & 63;
    int quad = lane >> 4, l15 = lane & 15;

    const float* xb = x + (size_t)b * CIN * HW_ + nt * NT;

    // ---- async DMA gather: 16 calls/wave, each 1 KB = 4 c-rows x 64 n ----
    // lane -> (c = c0 + lane/16, 16B at n = (lane&15)*4); LDS gets base+lane*16
    {
        const float* gl0 = xb + (size_t)(lane >> 4) * HW_ + (lane & 15) * 4;
        #pragma unroll
        for (int j = 0; j < 16; j++) {
            int c0 = w * 64 + j * 4;
            __builtin_amdgcn_global_load_lds(
                (const __attribute__((address_space(1))) unsigned int*)(gl0 + (size_t)c0 * HW_),
                (__attribute__((address_space(3))) unsigned int*)&xTf[c0 * 64],
                16, 0, 0);
        }
    }

    // per-wave a-range: a = w*64 + ai*16 + l15 (overlaps with DMA)
    float ga[4], wfv[4];
    #pragma unroll
    for (int ai = 0; ai < 4; ai++) {
        int a = w * 64 + ai * 16 + l15;
        ga[ai]  = ggbx[b * 256 + a];
        wfv[ai] = Wf[a];
    }

    float4_ acc[4][4];
    #pragma unroll
    for (int mi = 0; mi < 4; mi++)
        #pragma unroll
        for (int ai = 0; ai < 4; ai++)
            acc[mi][ai] = (float4_){0.f, 0.f, 0.f, 0.f};

    __syncthreads();                           // drains DMA (vmcnt) + barrier

    // ---- K loop: D[m=n][n'=a] = x^T * Wx^T ----
    const char* wsl = WxR + w * 32768 + lane * 16;   // wave's fragment slice
    short8 afA[4], bfA[4], afB[4], bfB[4];

    auto LDB = [&](short8* bf, int k0) {
        const char* wk = wsl + (k0 >> 5) * 4096;
        #pragma unroll
        for (int ai = 0; ai < 4; ai++)         // coalesced 1 KB per instr
            bf[ai] = *(const short8*)(wk + ai * 1024);
    };
    auto LDA = [&](short8* af, int k0) {       // fp32 LDS -> bf16 fragment
        int cb = k0 + quad * 8;
        #pragma unroll
        for (int mi = 0; mi < 4; mi++) {
            const float* bse = &xTf[cb * 64 + mi * 16 + l15];
            union { unsigned u[4]; short8 s; } cv;
            #pragma unroll
            for (int p = 0; p < 4; p++) {
                float f0 = bse[(2 * p) * 64];
                float f1 = bse[(2 * p + 1) * 64];
                cv.u[p] = f2bf(f0) | (f2bf(f1) << 16);
            }
            af[mi] = cv.s;
        }
    };
    auto MM = [&](short8* af, short8* bf) {
        #pragma unroll
        for (int mi = 0; mi < 4; mi++)
            #pragma unroll
            for (int ai = 0; ai < 4; ai++)
                acc[mi][ai] = __builtin_amdgcn_mfma_f32_16x16x32_bf16(
                    af[mi], bf[ai], acc[mi][ai], 0, 0, 0);
    };

    LDA(afA, 0);   LDB(bfA, 0);
    LDA(afB, 32);  LDB(bfB, 32);
    MM(afA, bfA);  LDA(afA, 64);  LDB(bfA, 64);
    MM(afB, bfB);  LDA(afB, 96);  LDB(bfB, 96);
    MM(afA, bfA);  LDA(afA, 128); LDB(bfA, 128);
    MM(afB, bfB);  LDA(afB, 160); LDB(bfB, 160);
    MM(afA, bfA);  LDA(afA, 192); LDB(bfA, 192);
    MM(afB, bfB);  LDA(afB, 224); LDB(bfB, 224);
    MM(afA, bfA);
    MM(afB, bfB);

    // ---- epilogue: relu(D + gg + bx) * Wf, reduce over a ----
    #pragma unroll
    for (int mi = 0; mi < 4; mi++) {
        float p[4] = {0.f, 0.f, 0.f, 0.f};
        #pragma unroll
        for (int ai = 0; ai < 4; ai++) {
            #pragma unroll
            for (int r = 0; r < 4; r++) {
                float vv = acc[mi][ai][r] + ga[ai];
                vv = fmaxf(vv, 0.f);
                p[r] = fmaf(vv, wfv[ai], p[r]);
            }
        }
        #pragma unroll
        for (int r = 0; r < 4; r++) {
            #pragma unroll
            for (int off = 1; off < 16; off <<= 1)
                p[r] += __shfl_xor(p[r], off, 16);
        }
        if (l15 == 0) {
            #pragma unroll
            for (int r = 0; r < 4; r++)
                att_part[w][mi * 16 + quad * 4 + r] = p[r];
        }
    }
    __syncthreads();

    if (t < NT) {
        float rv = att_part[0][t] + att_part[1][t] + att_part[2][t] + att_part[3][t] + bfs[0];
        raw[b * HW_ + nt * NT + t] = rv;
        raw_l[t] = rv;
    }
    __syncthreads();

    // ---- P/T pass (fp32 x): wave w covers c in [w*64, w*64+64) ----
    {
        float4_ rl = *(const float4_*)&raw_l[l15 * 4];
        #pragma unroll
        for (int ci = 0; ci < 16; ci++) {
            int c = w * 64 + ci * 4 + quad;
            float4_ xv = *(const float4_*)&xTf[c * 64 + l15 * 4];
            float pp = xv[0] * rl[0] + xv[1] * rl[1] + xv[2] * rl[2] + xv[3] * rl[3];
            float tt = (xv[0] + xv[1]) + (xv[2] + xv[3]);
            #pragma unroll
            for (int off = 1; off < 16; off <<= 1) {
                pp += __shfl_xor(pp, off, 16);
                tt += __shfl_xor(tt, off, 16);
            }
            if (l15 == 0) {
                atomicAdd(&P[b * 256 + c], pp);
                atomicAdd(&T[b * 256 + c], tt);
            }
        }
    }
}

// Kernel 2: per batch: min/sum over raw, write att output and pooled out
__global__ __launch_bounds__(256) void finalize_kernel(
    const float* __restrict__ raw, const float* __restrict__ P,
    const float* __restrict__ T, float* __restrict__ out)
{
    int b = blockIdx.x, t = threadIdx.x;
    const float* r = raw + (size_t)b * HW_;
    float v[16];
    float mn = 3.4e38f, sm = 0.f;
    #pragma unroll
    for (int i = 0; i < 16; i++) {
        v[i] = r[t + 256 * i];
        mn = fminf(mn, v[i]);
        sm += v[i];
    }
    #pragma unroll
    for (int off = 1; off < 64; off <<= 1) {
        mn = fminf(mn, __shfl_xor(mn, off, 64));
        sm += __shfl_xor(sm, off, 64);
    }
    __shared__ float smn[4], ssm[4];
    int w = t >> 6;
    if ((t & 63) == 0) { smn[w] = mn; ssm[w] = sm; }
    __syncthreads();
    mn = fminf(fminf(smn[0], smn[1]), fminf(smn[2], smn[3]));
    sm = (ssm[0] + ssm[1]) + (ssm[2] + ssm[3]);
    float S = sm - 4096.f * mn;                 // sum of (raw - min)
    float inv = 1.f / S;

    float* att = out + B_ * CIN + (size_t)b * HW_;
    #pragma unroll
    for (int i = 0; i < 16; i++) att[t + 256 * i] = (v[i] - mn) * inv;

    int ic = b * 256 + t;
    out[ic] = (P[ic] - mn * T[ic]) * inv;
}

extern "C" void kernel_launch(void* const* d_in, const int* in_sizes, int n_in,
                              void* d_out, int out_size, void* d_ws, size_t ws_size,
                              hipStream_t stream)
{
    const float* x   = (const float*)d_in[0];
    const float* g   = (const float*)d_in[1];
    const float* Wg  = (const float*)d_in[2];
    const float* bg  = (const float*)d_in[3];
    const float* Wx  = (const float*)d_in[4];
    const float* bx  = (const float*)d_in[5];
    const float* Wf  = (const float*)d_in[6];
    const float* bf  = (const float*)d_in[7];
    float* out = (float*)d_out;

    char* wsb = (char*)d_ws;
    uint4* WxR  = (uint4*)wsb;                            // 128 KB
    float* ggbx = (float*)(wsb + 131072);                 // 32 KB
    float* P    = ggbx + 8192;                            // 32 KB
    float* T    = P + 8192;                               // 32 KB
    float* raw  = T + 8192;                               // 512 KB

    prep_kernel<<<64, 256, 0, stream>>>(g, Wg, bg, Wx, bx, WxR, ggbx, P, T);
    attn_main<<<2048, 256, 0, stream>>>(x, (const char*)WxR, ggbx, Wf, bf, P, T, raw);
    finalize_kernel<<<32, 256, 0, stream>>>(raw, P, T, out);
}